// Round 1
// baseline (146.851 us; speedup 1.0000x reference)
//
#include <hip/hip_runtime.h>
#include <hip/hip_bf16.h>

typedef __bf16 bf16_t;
typedef __bf16 bf16x8 __attribute__((ext_vector_type(8)));
typedef float f32x4 __attribute__((ext_vector_type(4)));

#define MFMA16(a, b, c) __builtin_amdgcn_mfma_f32_16x16x32_bf16((a), (b), (c), 0, 0, 0)

static constexpr int BB = 4, SS = 1024, HH = 1024, NHEAD = 16, HDIM = 64;
static constexpr int MM = BB * SS;  // 4096

// ---------------- fp32 -> bf16 convert (hidden) ----------------
__global__ __launch_bounds__(256) void cvt_bf16_kernel(const float* __restrict__ in,
                                                       bf16_t* __restrict__ out, int n) {
  int i = (blockIdx.x * 256 + threadIdx.x) * 8;
  if (i >= n) return;
  float4 a = *(const float4*)(in + i);
  float4 b = *(const float4*)(in + i + 4);
  union { int4 i4; bf16_t h[8]; } u;
  u.h[0] = (bf16_t)a.x; u.h[1] = (bf16_t)a.y; u.h[2] = (bf16_t)a.z; u.h[3] = (bf16_t)a.w;
  u.h[4] = (bf16_t)b.x; u.h[5] = (bf16_t)b.y; u.h[6] = (bf16_t)b.z; u.h[7] = (bf16_t)b.w;
  *(int4*)(out + i) = u.i4;
}

// ---------------- W [k][n] fp32 -> WT [n][k] bf16 ----------------
__global__ __launch_bounds__(256) void transposeW_kernel(const float* __restrict__ Wq,
                                                         const float* __restrict__ Wk,
                                                         const float* __restrict__ Wv,
                                                         bf16_t* __restrict__ WT) {
  __shared__ float tile[32][33];
  int z = blockIdx.z;
  const float* W = (z == 0) ? Wq : (z == 1) ? Wk : Wv;
  bf16_t* Out = WT + (size_t)z * HH * HH;
  int tx = threadIdx.x, ty = threadIdx.y;
  int x0 = blockIdx.x * 32;  // n
  int y0 = blockIdx.y * 32;  // k
  for (int j = ty; j < 32; j += 8)
    tile[j][tx] = W[(size_t)(y0 + j) * HH + x0 + tx];
  __syncthreads();
  for (int j = ty; j < 32; j += 8)
    Out[(size_t)(x0 + j) * HH + y0 + tx] = (bf16_t)tile[tx][j];
}

// ---------------- QKV projection GEMM ----------------
// C[m][n] = hiddenB[m][:] . WT[n][:] + bias[n], stored to [b][h][s][d] bf16
#define GM 128
#define GN 128
#define GK 32
#define APAD 40  // bf16 elems per row (80B, 16B aligned)

__global__ __launch_bounds__(256) void qkv_gemm_kernel(const bf16_t* __restrict__ hiddenB,
                                                       const bf16_t* __restrict__ WT,
                                                       const float* __restrict__ bq,
                                                       const float* __restrict__ bk,
                                                       const float* __restrict__ bv,
                                                       bf16_t* __restrict__ QKV) {
  __shared__ bf16_t Asm[GM * APAD];
  __shared__ bf16_t Bsm[GN * APAD];
  const int z = blockIdx.z;
  const bf16_t* Wt = WT + (size_t)z * HH * HH;
  const float* bias = (z == 0) ? bq : (z == 1) ? bk : bv;
  bf16_t* Out = QKV + (size_t)z * MM * HH;

  const int m0 = blockIdx.y * GM;
  const int n0 = blockIdx.x * GN;
  const int t = threadIdx.x;
  const int lane = t & 63;
  const int wave = t >> 6;
  const int wm = wave >> 1, wn = wave & 1;
  const int lr = lane & 15;
  const int hi = lane >> 4;

  f32x4 acc[4][4] = {};

  const int sr = t >> 1;
  const int sc = (t & 1) * 16;

  for (int k0 = 0; k0 < HH; k0 += GK) {
    const bf16_t* ga = hiddenB + (size_t)(m0 + sr) * HH + k0 + sc;
    int4 a0 = *(const int4*)(ga);
    int4 a1 = *(const int4*)(ga + 8);
    const bf16_t* gb = Wt + (size_t)(n0 + sr) * HH + k0 + sc;
    int4 b0 = *(const int4*)(gb);
    int4 b1 = *(const int4*)(gb + 8);
    *(int4*)&Asm[sr * APAD + sc] = a0;
    *(int4*)&Asm[sr * APAD + sc + 8] = a1;
    *(int4*)&Bsm[sr * APAD + sc] = b0;
    *(int4*)&Bsm[sr * APAD + sc + 8] = b1;
    __syncthreads();

    bf16x8 af[4], bfr[4];
#pragma unroll
    for (int mi = 0; mi < 4; ++mi)
      af[mi] = *(const bf16x8*)&Asm[(wm * 64 + mi * 16 + lr) * APAD + hi * 8];
#pragma unroll
    for (int ni = 0; ni < 4; ++ni)
      bfr[ni] = *(const bf16x8*)&Bsm[(wn * 64 + ni * 16 + lr) * APAD + hi * 8];
#pragma unroll
    for (int mi = 0; mi < 4; ++mi)
#pragma unroll
      for (int ni = 0; ni < 4; ++ni)
        acc[mi][ni] = MFMA16(af[mi], bfr[ni], acc[mi][ni]);
    __syncthreads();
  }

  // epilogue: + bias, cast bf16, scatter to [b][h][s][d]
#pragma unroll
  for (int ni = 0; ni < 4; ++ni) {
    int col = n0 + wn * 64 + ni * 16 + lr;
    float bia = bias[col];
    int h = col >> 6, d = col & 63;
#pragma unroll
    for (int mi = 0; mi < 4; ++mi) {
#pragma unroll
      for (int r = 0; r < 4; ++r) {
        int row = m0 + wm * 64 + mi * 16 + hi * 4 + r;  // = b*S + s
        int b = row >> 10, s = row & 1023;
        float val = acc[mi][ni][r] + bia;
        Out[((size_t)(b * NHEAD + h) * SS + s) * HDIM + d] = (bf16_t)val;
      }
    }
  }
}

// ---------------- fused flash attention ----------------
#define SPAD 72  // padded LDS row stride in bf16 (144B, 16B aligned)

__global__ __launch_bounds__(256) void attn_kernel(const bf16_t* __restrict__ Q,
                                                   const bf16_t* __restrict__ K,
                                                   const bf16_t* __restrict__ V,
                                                   const float* __restrict__ mask,
                                                   float* __restrict__ out) {
  __shared__ bf16_t Ksm[64 * SPAD];
  __shared__ bf16_t Vtsm[64 * SPAD];  // transposed: [d][kv]
  __shared__ bf16_t Psm[4 * 16 * SPAD];

  const int bh = blockIdx.y;       // b*16 + h
  const int b = bh >> 4;
  const int h = bh & 15;
  const int t = threadIdx.x;
  const int lane = t & 63;
  const int wave = t >> 6;
  const int lr = lane & 15;
  const int hi = lane >> 4;
  const int q0 = blockIdx.x * 64 + wave * 16;

  const bf16_t* Qh = Q + (size_t)bh * SS * HDIM;
  const bf16_t* Kh = K + (size_t)bh * SS * HDIM;
  const bf16_t* Vh = V + (size_t)bh * SS * HDIM;
  const float* mrow = mask + (size_t)b * SS;

  // Q fragments for this wave's 16 rows (row = lr, k = hi*8+i per 32-chunk)
  bf16x8 qa[2];
#pragma unroll
  for (int c = 0; c < 2; ++c)
    qa[c] = *(const bf16x8*)&Qh[(size_t)(q0 + lr) * HDIM + c * 32 + hi * 8];

  f32x4 of[4] = {};
  float m_run[4], l_run[4];
#pragma unroll
  for (int r = 0; r < 4; ++r) { m_run[r] = -1e30f; l_run[r] = 0.f; }

  const int sr = t >> 2;         // 0..63 (kv row)
  const int sc = (t & 3) * 16;   // d segment

  for (int kv0 = 0; kv0 < SS; kv0 += 64) {
    // ---- stage K (row-major, padded) and V (transposed) ----
    {
      const bf16_t* gk = Kh + (size_t)(kv0 + sr) * HDIM + sc;
      int4 k0v = *(const int4*)gk;
      int4 k1v = *(const int4*)(gk + 8);
      *(int4*)&Ksm[sr * SPAD + sc] = k0v;
      *(int4*)&Ksm[sr * SPAD + sc + 8] = k1v;
      const bf16_t* gv = Vh + (size_t)(kv0 + sr) * HDIM + sc;
      union { int4 i4; unsigned short u[8]; } v0, v1;
      v0.i4 = *(const int4*)gv;
      v1.i4 = *(const int4*)(gv + 8);
      unsigned short* vt = (unsigned short*)Vtsm;
#pragma unroll
      for (int e = 0; e < 8; ++e) {
        vt[(sc + e) * SPAD + sr] = v0.u[e];
        vt[(sc + 8 + e) * SPAD + sr] = v1.u[e];
      }
    }
    __syncthreads();

    // ---- S = (Q K^T) * scale + mask ----
    f32x4 sf[4];
#pragma unroll
    for (int nf = 0; nf < 4; ++nf) {
      bf16x8 kb0 = *(const bf16x8*)&Ksm[(nf * 16 + lr) * SPAD + 0 + hi * 8];
      bf16x8 kb1 = *(const bf16x8*)&Ksm[(nf * 16 + lr) * SPAD + 32 + hi * 8];
      f32x4 s = {};
      s = MFMA16(qa[0], kb0, s);
      s = MFMA16(qa[1], kb1, s);
      sf[nf] = s;
    }
    float mk[4];
#pragma unroll
    for (int nf = 0; nf < 4; ++nf) mk[nf] = mrow[kv0 + nf * 16 + lr];
#pragma unroll
    for (int nf = 0; nf < 4; ++nf)
#pragma unroll
      for (int r = 0; r < 4; ++r)
        sf[nf][r] = sf[nf][r] * 0.125f + mk[nf];

    // ---- online softmax ----
    float corr[4], tsum[4];
#pragma unroll
    for (int r = 0; r < 4; ++r) {
      float v = fmaxf(fmaxf(sf[0][r], sf[1][r]), fmaxf(sf[2][r], sf[3][r]));
      v = fmaxf(v, __shfl_xor(v, 1));
      v = fmaxf(v, __shfl_xor(v, 2));
      v = fmaxf(v, __shfl_xor(v, 4));
      v = fmaxf(v, __shfl_xor(v, 8));
      float mn = fmaxf(m_run[r], v);
      corr[r] = __expf(m_run[r] - mn);
      m_run[r] = mn;
      tsum[r] = 0.f;
    }
#pragma unroll
    for (int nf = 0; nf < 4; ++nf) {
#pragma unroll
      for (int r = 0; r < 4; ++r) {
        float p = __expf(sf[nf][r] - m_run[r]);
        tsum[r] += p;
        Psm[(wave * 16 + hi * 4 + r) * SPAD + nf * 16 + lr] = (bf16_t)p;
      }
    }
#pragma unroll
    for (int r = 0; r < 4; ++r) {
      float v = tsum[r];
      v += __shfl_xor(v, 1);
      v += __shfl_xor(v, 2);
      v += __shfl_xor(v, 4);
      v += __shfl_xor(v, 8);
      l_run[r] = l_run[r] * corr[r] + v;
    }
#pragma unroll
    for (int df = 0; df < 4; ++df)
#pragma unroll
      for (int r = 0; r < 4; ++r)
        of[df][r] *= corr[r];

    // ---- O += P V  (P via per-wave LDS re-layout; DS ops in-order per wave) ----
#pragma unroll
    for (int c = 0; c < 2; ++c) {
      bf16x8 pa = *(const bf16x8*)&Psm[(wave * 16 + lr) * SPAD + c * 32 + hi * 8];
#pragma unroll
      for (int df = 0; df < 4; ++df) {
        bf16x8 vb = *(const bf16x8*)&Vtsm[(df * 16 + lr) * SPAD + c * 32 + hi * 8];
        of[df] = MFMA16(pa, vb, of[df]);
      }
    }
    __syncthreads();
  }

  // ---- epilogue: normalize, write [b][s][h*64+d] fp32 ----
#pragma unroll
  for (int df = 0; df < 4; ++df) {
#pragma unroll
    for (int r = 0; r < 4; ++r) {
      int q = q0 + hi * 4 + r;
      out[((size_t)(b * SS + q)) * HH + h * HDIM + df * 16 + lr] = of[df][r] / l_run[r];
    }
  }
}

// ---------------- launch ----------------
extern "C" void kernel_launch(void* const* d_in, const int* in_sizes, int n_in,
                              void* d_out, int out_size, void* d_ws, size_t ws_size,
                              hipStream_t stream) {
  const float* hs   = (const float*)d_in[0];
  const float* mask = (const float*)d_in[1];
  const float* Wq   = (const float*)d_in[2];
  const float* bq   = (const float*)d_in[3];
  const float* Wk   = (const float*)d_in[4];
  const float* bk   = (const float*)d_in[5];
  const float* Wv   = (const float*)d_in[6];
  const float* bv   = (const float*)d_in[7];
  float* out = (float*)d_out;

  char* ws = (char*)d_ws;
  bf16_t* hiddenB = (bf16_t*)ws;                                  // 8 MB
  bf16_t* WT      = (bf16_t*)(ws + (size_t)8 * 1024 * 1024);      // 6 MB
  bf16_t* QKV     = (bf16_t*)(ws + (size_t)14 * 1024 * 1024);     // 24 MB

  cvt_bf16_kernel<<<MM * HH / (256 * 8), 256, 0, stream>>>(hs, hiddenB, MM * HH);
  transposeW_kernel<<<dim3(32, 32, 3), dim3(32, 8), 0, stream>>>(Wq, Wk, Wv, WT);
  qkv_gemm_kernel<<<dim3(HH / GN, MM / GM, 3), 256, 0, stream>>>(hiddenB, WT, bq, bk, bv, QKV);
  attn_kernel<<<dim3(SS / 64, BB * NHEAD), 256, 0, stream>>>(
      QKV, QKV + (size_t)MM * HH, QKV + (size_t)2 * MM * HH, mask, out);
}

// Round 2
// 119.148 us; speedup vs baseline: 1.2325x; 1.2325x over previous
//
#include <hip/hip_runtime.h>
#include <hip/hip_bf16.h>

typedef __bf16 bf16_t;
typedef __bf16 bf16x8 __attribute__((ext_vector_type(8)));
typedef float f32x4 __attribute__((ext_vector_type(4)));
typedef float f32x16 __attribute__((ext_vector_type(16)));
typedef unsigned uint2v __attribute__((ext_vector_type(2)));

#define MFMA16(a, b, c) __builtin_amdgcn_mfma_f32_16x16x32_bf16((a), (b), (c), 0, 0, 0)
#define MFMA32(a, b, c) __builtin_amdgcn_mfma_f32_32x32x16_bf16((a), (b), (c), 0, 0, 0)

static constexpr int BB = 4, SS = 1024, HH = 1024, NHEAD = 16, HDIM = 64;
static constexpr int MM = BB * SS;  // 4096

__device__ __forceinline__ void gload_lds16(const void* g, void* l) {
  __builtin_amdgcn_global_load_lds((const __attribute__((address_space(1))) void*)g,
                                   (__attribute__((address_space(3))) void*)l, 16, 0, 0);
}

#if __has_builtin(__builtin_amdgcn_permlane32_swap)
#define PSWAP(a, b)                                                    \
  {                                                                    \
    uint2v _r = __builtin_amdgcn_permlane32_swap((a), (b), false, false); \
    (a) = _r.x;                                                        \
    (b) = _r.y;                                                        \
  }
#else
#define PSWAP(a, b) asm("v_permlane32_swap_b32 %0, %1" : "+v"(a), "+v"(b))
#endif

// ---------------- fp32 -> bf16 convert (hidden) ----------------
__global__ __launch_bounds__(256) void cvt_bf16_kernel(const float* __restrict__ in,
                                                       bf16_t* __restrict__ out, int n) {
  int i = (blockIdx.x * 256 + threadIdx.x) * 8;
  if (i >= n) return;
  float4 a = *(const float4*)(in + i);
  float4 b = *(const float4*)(in + i + 4);
  union { int4 i4; bf16_t h[8]; } u;
  u.h[0] = (bf16_t)a.x; u.h[1] = (bf16_t)a.y; u.h[2] = (bf16_t)a.z; u.h[3] = (bf16_t)a.w;
  u.h[4] = (bf16_t)b.x; u.h[5] = (bf16_t)b.y; u.h[6] = (bf16_t)b.z; u.h[7] = (bf16_t)b.w;
  *(int4*)(out + i) = u.i4;
}

// ---------------- W [k][n] fp32 -> WT [n][k] bf16 ----------------
__global__ __launch_bounds__(256) void transposeW_kernel(const float* __restrict__ Wq,
                                                         const float* __restrict__ Wk,
                                                         const float* __restrict__ Wv,
                                                         bf16_t* __restrict__ WT) {
  __shared__ float tile[32][33];
  int z = blockIdx.z;
  const float* W = (z == 0) ? Wq : (z == 1) ? Wk : Wv;
  bf16_t* Out = WT + (size_t)z * HH * HH;
  int tx = threadIdx.x, ty = threadIdx.y;
  int x0 = blockIdx.x * 32;  // n
  int y0 = blockIdx.y * 32;  // k
  for (int j = ty; j < 32; j += 8)
    tile[j][tx] = W[(size_t)(y0 + j) * HH + x0 + tx];
  __syncthreads();
  for (int j = ty; j < 32; j += 8)
    Out[(size_t)(x0 + j) * HH + y0 + tx] = (bf16_t)tile[tx][j];
}

// ---------------- QKV projection GEMM ----------------
#define GM 128
#define GN 128
#define GK 32
#define APAD 40  // bf16 elems per row (80B, 16B aligned)

__global__ __launch_bounds__(256) void qkv_gemm_kernel(const bf16_t* __restrict__ hiddenB,
                                                       const bf16_t* __restrict__ WT,
                                                       const float* __restrict__ bq,
                                                       const float* __restrict__ bk,
                                                       const float* __restrict__ bv,
                                                       bf16_t* __restrict__ QKV) {
  __shared__ bf16_t Asm[GM * APAD];
  __shared__ bf16_t Bsm[GN * APAD];
  const int z = blockIdx.z;
  const bf16_t* Wt = WT + (size_t)z * HH * HH;
  const float* bias = (z == 0) ? bq : (z == 1) ? bk : bv;
  bf16_t* Out = QKV + (size_t)z * MM * HH;

  const int m0 = blockIdx.y * GM;
  const int n0 = blockIdx.x * GN;
  const int t = threadIdx.x;
  const int lane = t & 63;
  const int wave = t >> 6;
  const int wm = wave >> 1, wn = wave & 1;
  const int lr = lane & 15;
  const int hi = lane >> 4;

  f32x4 acc[4][4] = {};

  const int sr = t >> 1;
  const int sc = (t & 1) * 16;

  for (int k0 = 0; k0 < HH; k0 += GK) {
    const bf16_t* ga = hiddenB + (size_t)(m0 + sr) * HH + k0 + sc;
    int4 a0 = *(const int4*)(ga);
    int4 a1 = *(const int4*)(ga + 8);
    const bf16_t* gb = Wt + (size_t)(n0 + sr) * HH + k0 + sc;
    int4 b0 = *(const int4*)(gb);
    int4 b1 = *(const int4*)(gb + 8);
    *(int4*)&Asm[sr * APAD + sc] = a0;
    *(int4*)&Asm[sr * APAD + sc + 8] = a1;
    *(int4*)&Bsm[sr * APAD + sc] = b0;
    *(int4*)&Bsm[sr * APAD + sc + 8] = b1;
    __syncthreads();

    bf16x8 af[4], bfr[4];
#pragma unroll
    for (int mi = 0; mi < 4; ++mi)
      af[mi] = *(const bf16x8*)&Asm[(wm * 64 + mi * 16 + lr) * APAD + hi * 8];
#pragma unroll
    for (int ni = 0; ni < 4; ++ni)
      bfr[ni] = *(const bf16x8*)&Bsm[(wn * 64 + ni * 16 + lr) * APAD + hi * 8];
#pragma unroll
    for (int mi = 0; mi < 4; ++mi)
#pragma unroll
      for (int ni = 0; ni < 4; ++ni)
        acc[mi][ni] = MFMA16(af[mi], bfr[ni], acc[mi][ni]);
    __syncthreads();
  }

#pragma unroll
  for (int ni = 0; ni < 4; ++ni) {
    int col = n0 + wn * 64 + ni * 16 + lr;
    float bia = bias[col];
    int h = col >> 6, d = col & 63;
#pragma unroll
    for (int mi = 0; mi < 4; ++mi) {
#pragma unroll
      for (int r = 0; r < 4; ++r) {
        int row = m0 + wm * 64 + mi * 16 + hi * 4 + r;  // = b*S + s
        int b = row >> 10, s = row & 1023;
        float val = acc[mi][ni][r] + bia;
        Out[((size_t)(b * NHEAD + h) * SS + s) * HDIM + d] = (bf16_t)val;
      }
    }
  }
}

// ---------------- V [bh][s][d] -> Vt [bh][d][s] ----------------
__global__ __launch_bounds__(256) void vtrans_kernel(const bf16_t* __restrict__ V,
                                                     bf16_t* __restrict__ Vt) {
  __shared__ bf16_t T[64 * 72];
  const int bh = blockIdx.y;
  const int s0 = blockIdx.x * 64;
  const int t = threadIdx.x;
  const bf16_t* Vb = V + (size_t)bh * SS * HDIM;
  bf16_t* Vtb = Vt + (size_t)bh * HDIM * SS;
#pragma unroll
  for (int it = 0; it < 2; ++it) {
    int idx = t + it * 256;
    int sl = idx >> 3;
    int dc = (idx & 7) * 8;
    *(int4*)&T[sl * 72 + dc] = *(const int4*)&Vb[(size_t)(s0 + sl) * HDIM + dc];
  }
  __syncthreads();
#pragma unroll
  for (int it = 0; it < 2; ++it) {
    int idx = t + it * 256;
    int d = idx >> 3;
    int sc = (idx & 7) * 8;
    union { int4 i4; bf16_t h[8]; } u;
#pragma unroll
    for (int e = 0; e < 8; ++e) u.h[e] = T[(sc + e) * 72 + d];
    *(int4*)&Vtb[(size_t)d * SS + s0 + sc] = u.i4;
  }
}

// ---------------- fused flash attention (swapped QK^T, 32x32 MFMA) ----------------
// Per block: 4 waves x 32 q-rows = 128 q. KV step = 64.
// K LDS [kv][64d] rows 128B, XOR-swizzled (byte ^= (row&7)<<4), staged via global_load_lds
// with pre-swizzled global source. Vt LDS [d][64kv] same scheme from Vt[bh][d][s].
// S^T = mfma32(K, Q): lane holds col q=lane&31, rows kv=(reg&3)+8*(reg>>2)+4*hi.
// P^T B-frags built in-register via cvt_pk_bf16 + permlane32_swap.
// O^T = mfma32(V^T, P^T): lane holds col q, rows d (same pattern) -> softmax state lane-aligned.
__global__ __launch_bounds__(256) void attn2_kernel(const bf16_t* __restrict__ Q,
                                                    const bf16_t* __restrict__ K,
                                                    const bf16_t* __restrict__ Vt,
                                                    const float* __restrict__ mask,
                                                    float* __restrict__ out) {
  __shared__ bf16_t Ksm[64 * 64];
  __shared__ bf16_t Vsm[64 * 64];
  __shared__ float Msm[SS];

  const int bh = blockIdx.y;
  const int b = bh >> 4;
  const int h = bh & 15;
  const int t = threadIdx.x;
  const int lane = t & 63;
  const int w = t >> 6;
  const int l31 = lane & 31;
  const int hi = lane >> 5;
  const int q0 = blockIdx.x * 128 + w * 32;

  const bf16_t* Qh = Q + (size_t)bh * SS * HDIM;
  const bf16_t* Kh = K + (size_t)bh * SS * HDIM;
  const bf16_t* Vh = Vt + (size_t)bh * HDIM * SS;  // [d][s]

  // stage mask for this batch (broadcast reads later)
  *(float4*)&Msm[t * 4] = *(const float4*)&mask[(size_t)b * SS + t * 4];

  // Q fragments (B-operand): lane holds q = q0+l31, k = c*16 + hi*8 + i
  bf16x8 qb[4];
#pragma unroll
  for (int c = 0; c < 4; ++c)
    qb[c] = *(const bf16x8*)&Qh[(size_t)(q0 + l31) * HDIM + c * 16 + hi * 8];

  // staging source swizzle (constant per lane)
  const int srow = lane >> 3;                              // 0..7
  const unsigned gcol = ((lane & 7) * 16) ^ (srow << 4);   // bytes within 128B row
  const unsigned swz = (unsigned)((l31 & 7) << 4);         // read-side swizzle

  f32x16 acc0 = {}, acc1 = {};
  float m_run = -1e30f, l_run = 0.f;

  for (int kv0 = 0; kv0 < SS; kv0 += 64) {
    // ---- stage K tile rows [kv0..kv0+64) and Vt rows d=[0..64) at cols [kv0..kv0+64) ----
#pragma unroll
    for (int i = 0; i < 2; ++i) {
      int rbase = w * 16 + i * 8;
      gload_lds16((const char*)Kh + (size_t)(kv0 + rbase + srow) * 128 + gcol,
                  (char*)Ksm + (size_t)rbase * 128);
      gload_lds16((const char*)Vh + (size_t)(rbase + srow) * 2048 + (size_t)kv0 * 2 + gcol,
                  (char*)Vsm + (size_t)rbase * 128);
    }
    __syncthreads();

#pragma unroll
    for (int j = 0; j < 2; ++j) {
      // ---- S^T = K . Q^T ----
      f32x16 st = {};
#pragma unroll
      for (int c = 0; c < 4; ++c) {
        bf16x8 kf = *(const bf16x8*)((const char*)Ksm + (size_t)(j * 32 + l31) * 128 +
                                     ((unsigned)(c * 32 + hi * 16) ^ swz));
        st = MFMA32(kf, qb[c], st);
      }
      // ---- scale + mask ----
#pragma unroll
      for (int k2 = 0; k2 < 8; ++k2) {
        int off = 8 * (k2 >> 1) + 4 * hi + 2 * (k2 & 1);
        float2 mk = *(const float2*)&Msm[kv0 + j * 32 + off];
        st[2 * k2] = st[2 * k2] * 0.125f + mk.x;
        st[2 * k2 + 1] = st[2 * k2 + 1] * 0.125f + mk.y;
      }
      // ---- online softmax (per q = lane&31; pair lane^32 holds other 16 kv) ----
      float mj = st[0];
#pragma unroll
      for (int r = 1; r < 16; ++r) mj = fmaxf(mj, st[r]);
      mj = fmaxf(mj, __shfl_xor(mj, 32));
      if (!__all(mj <= m_run + 8.f)) {
        float mnew = fmaxf(m_run, mj);
        float corr = __expf(m_run - mnew);
#pragma unroll
        for (int r = 0; r < 16; ++r) { acc0[r] *= corr; acc1[r] *= corr; }
        l_run *= corr;
        m_run = mnew;
      }
      float ls = 0.f;
#pragma unroll
      for (int r = 0; r < 16; ++r) {
        float p = __expf(st[r] - m_run);
        st[r] = p;
        ls += p;
      }
      ls += __shfl_xor(ls, 32);
      l_run += ls;
      // ---- pack P^T into B-frags: cvt_pk + permlane32_swap ----
      unsigned wd[8];
#pragma unroll
      for (int k2 = 0; k2 < 8; ++k2) {
        float lo = st[2 * k2], hip = st[2 * k2 + 1];
        unsigned r;
        asm("v_cvt_pk_bf16_f32 %0, %1, %2" : "=v"(r) : "v"(lo), "v"(hip));
        wd[k2] = r;
      }
      unsigned a0 = wd[0], b0 = wd[2]; PSWAP(a0, b0);
      unsigned a1 = wd[1], b1 = wd[3]; PSWAP(a1, b1);
      unsigned a2 = wd[4], b2 = wd[6]; PSWAP(a2, b2);
      unsigned a3 = wd[5], b3 = wd[7]; PSWAP(a3, b3);
      union { unsigned u[4]; bf16x8 v; } pf0, pf1;
      pf0.u[0] = a0; pf0.u[1] = a1; pf0.u[2] = b0; pf0.u[3] = b1;
      pf1.u[0] = a2; pf1.u[1] = a3; pf1.u[2] = b2; pf1.u[3] = b3;
      // ---- O^T += V^T . P^T ----
#pragma unroll
      for (int kvc = 0; kvc < 2; ++kvc) {
        bf16x8 pf = (kvc == 0) ? pf0.v : pf1.v;
#pragma unroll
        for (int dch = 0; dch < 2; ++dch) {
          bf16x8 vf = *(const bf16x8*)((const char*)Vsm + (size_t)(dch * 32 + l31) * 128 +
                                       ((unsigned)(j * 64 + kvc * 32 + hi * 16) ^ swz));
          if (dch == 0) acc0 = MFMA32(vf, pf, acc0);
          else          acc1 = MFMA32(vf, pf, acc1);
        }
      }
    }
    __syncthreads();
  }

  // ---- epilogue: normalize, write fp32 [b][s=q][h*64+d] ----
  float rinv = 1.0f / l_run;
  int q = q0 + l31;
  float* ob = out + ((size_t)(b * SS + q)) * HH + h * HDIM;
#pragma unroll
  for (int g = 0; g < 4; ++g) {
    float4 o0, o1;
    o0.x = acc0[g * 4 + 0] * rinv; o0.y = acc0[g * 4 + 1] * rinv;
    o0.z = acc0[g * 4 + 2] * rinv; o0.w = acc0[g * 4 + 3] * rinv;
    o1.x = acc1[g * 4 + 0] * rinv; o1.y = acc1[g * 4 + 1] * rinv;
    o1.z = acc1[g * 4 + 2] * rinv; o1.w = acc1[g * 4 + 3] * rinv;
    *(float4*)&ob[g * 8 + 4 * hi] = o0;
    *(float4*)&ob[32 + g * 8 + 4 * hi] = o1;
  }
}

// ---------------- launch ----------------
extern "C" void kernel_launch(void* const* d_in, const int* in_sizes, int n_in,
                              void* d_out, int out_size, void* d_ws, size_t ws_size,
                              hipStream_t stream) {
  const float* hs   = (const float*)d_in[0];
  const float* mask = (const float*)d_in[1];
  const float* Wq   = (const float*)d_in[2];
  const float* bq   = (const float*)d_in[3];
  const float* Wk   = (const float*)d_in[4];
  const float* bk   = (const float*)d_in[5];
  const float* Wv   = (const float*)d_in[6];
  const float* bv   = (const float*)d_in[7];
  float* out = (float*)d_out;

  char* ws = (char*)d_ws;
  bf16_t* hiddenB = (bf16_t*)ws;                                  // 8 MB (dead after GEMM)
  bf16_t* WT      = (bf16_t*)(ws + (size_t)8 * 1024 * 1024);      // 6 MB
  bf16_t* QKV     = (bf16_t*)(ws + (size_t)14 * 1024 * 1024);     // 24 MB
  bf16_t* Vt      = (bf16_t*)ws;                                  // reuse hiddenB region (8 MB)

  cvt_bf16_kernel<<<MM * HH / (256 * 8), 256, 0, stream>>>(hs, hiddenB, MM * HH);
  transposeW_kernel<<<dim3(32, 32, 3), dim3(32, 8), 0, stream>>>(Wq, Wk, Wv, WT);
  qkv_gemm_kernel<<<dim3(HH / GN, MM / GM, 3), 256, 0, stream>>>(hiddenB, WT, bq, bk, bv, QKV);
  vtrans_kernel<<<dim3(SS / 64, BB * NHEAD), 256, 0, stream>>>(QKV + (size_t)2 * MM * HH, Vt);
  attn2_kernel<<<dim3(SS / 128, BB * NHEAD), 256, 0, stream>>>(
      QKV, QKV + (size_t)MM * HH, Vt, mask, out);
}

// Round 3
// 100.854 us; speedup vs baseline: 1.4561x; 1.1814x over previous
//
#include <hip/hip_runtime.h>
#include <hip/hip_bf16.h>

typedef __bf16 bf16_t;
typedef __bf16 bf16x8 __attribute__((ext_vector_type(8)));
typedef float f32x4 __attribute__((ext_vector_type(4)));
typedef float f32x16 __attribute__((ext_vector_type(16)));
typedef unsigned uint2v __attribute__((ext_vector_type(2)));

#define MFMA16(a, b, c) __builtin_amdgcn_mfma_f32_16x16x32_bf16((a), (b), (c), 0, 0, 0)
#define MFMA32(a, b, c) __builtin_amdgcn_mfma_f32_32x32x16_bf16((a), (b), (c), 0, 0, 0)

static constexpr int BB = 4, SS = 1024, HH = 1024, NHEAD = 16, HDIM = 64;
static constexpr int MM = BB * SS;  // 4096

__device__ __forceinline__ void gload_lds16(const void* g, void* l) {
  __builtin_amdgcn_global_load_lds((const __attribute__((address_space(1))) void*)g,
                                   (__attribute__((address_space(3))) void*)l, 16, 0, 0);
}

#if __has_builtin(__builtin_amdgcn_permlane32_swap)
#define PSWAP(a, b)                                                    \
  {                                                                    \
    uint2v _r = __builtin_amdgcn_permlane32_swap((a), (b), false, false); \
    (a) = _r.x;                                                        \
    (b) = _r.y;                                                        \
  }
#else
#define PSWAP(a, b) asm("v_permlane32_swap_b32 %0, %1" : "+v"(a), "+v"(b))
#endif

// ---------------- fp32 -> bf16 convert (hidden) ----------------
__global__ __launch_bounds__(256) void cvt_bf16_kernel(const float* __restrict__ in,
                                                       bf16_t* __restrict__ out, int n) {
  int i = (blockIdx.x * 256 + threadIdx.x) * 8;
  if (i >= n) return;
  float4 a = *(const float4*)(in + i);
  float4 b = *(const float4*)(in + i + 4);
  union { int4 i4; bf16_t h[8]; } u;
  u.h[0] = (bf16_t)a.x; u.h[1] = (bf16_t)a.y; u.h[2] = (bf16_t)a.z; u.h[3] = (bf16_t)a.w;
  u.h[4] = (bf16_t)b.x; u.h[5] = (bf16_t)b.y; u.h[6] = (bf16_t)b.z; u.h[7] = (bf16_t)b.w;
  *(int4*)(out + i) = u.i4;
}

// ---------------- W [k][n] fp32 -> WT [n][k] bf16 ----------------
__global__ __launch_bounds__(256) void transposeW_kernel(const float* __restrict__ Wq,
                                                         const float* __restrict__ Wk,
                                                         const float* __restrict__ Wv,
                                                         bf16_t* __restrict__ WT) {
  __shared__ float tile[32][33];
  int z = blockIdx.z;
  const float* W = (z == 0) ? Wq : (z == 1) ? Wk : Wv;
  bf16_t* Out = WT + (size_t)z * HH * HH;
  int tx = threadIdx.x, ty = threadIdx.y;
  int x0 = blockIdx.x * 32;  // n
  int y0 = blockIdx.y * 32;  // k
  for (int j = ty; j < 32; j += 8)
    tile[j][tx] = W[(size_t)(y0 + j) * HH + x0 + tx];
  __syncthreads();
  for (int j = ty; j < 32; j += 8)
    Out[(size_t)(x0 + j) * HH + y0 + tx] = (bf16_t)tile[tx][j];
}

// ---------------- QKV projection GEMM (m97 structure) ----------------
// 128x128 tile, BK=64 (128B rows), global_load_lds w16 staging with
// pre-swizzled source (byte ^= (row&7)<<4), swizzled ds_read_b128 frags.
#define GM 128
#define GN 128
#define BK 64

__global__ __launch_bounds__(256) void qkv_gemm_kernel(const bf16_t* __restrict__ hiddenB,
                                                       const bf16_t* __restrict__ WT,
                                                       const float* __restrict__ bq,
                                                       const float* __restrict__ bk,
                                                       const float* __restrict__ bv,
                                                       bf16_t* __restrict__ QKV) {
  __shared__ bf16_t Asm[GM * BK];  // 16 KB
  __shared__ bf16_t Bsm[GN * BK];  // 16 KB

  // chunked XCD swizzle: 768 wgs, 96 per XCD; n fastest -> A panel stays on one XCD
  const int wg = blockIdx.x;
  const int swz = (wg & 7) * 96 + (wg >> 3);
  const int nblk = swz & 7;
  const int mblk = (swz >> 3) & 31;
  const int z = swz >> 8;

  const bf16_t* Wt = WT + (size_t)z * HH * HH;
  const float* bias = (z == 0) ? bq : (z == 1) ? bk : bv;
  bf16_t* Out = QKV + (size_t)z * MM * HH;

  const int m0 = mblk * GM;
  const int n0 = nblk * GN;
  const int t = threadIdx.x;
  const int lane = t & 63;
  const int w = t >> 6;
  const int wm = w >> 1, wn = w & 1;
  const int lr = lane & 15;
  const int hi = lane >> 4;

  // staging: per (i,w): rows rb..rb+8 of the tile, lane covers row rb+(lane>>3),
  // 16B chunk (lane&7), source column XOR-swizzled by row
  const int srow = lane >> 3;
  const unsigned gcol = ((unsigned)(lane & 7) << 4) ^ ((unsigned)srow << 4);
  const char* Abase = (const char*)(hiddenB + (size_t)m0 * HH);
  const char* Bbase = (const char*)(Wt + (size_t)n0 * HH);

  f32x4 acc[4][4] = {};

  for (int k0 = 0; k0 < HH; k0 += BK) {
#pragma unroll
    for (int i = 0; i < 4; ++i) {
      const int rb = (i * 4 + w) * 8;
      gload_lds16(Abase + (size_t)(rb + srow) * 2048 + k0 * 2 + gcol, (char*)Asm + rb * 128);
      gload_lds16(Bbase + (size_t)(rb + srow) * 2048 + k0 * 2 + gcol, (char*)Bsm + rb * 128);
    }
    __syncthreads();

#pragma unroll
    for (int kk = 0; kk < 2; ++kk) {
      const unsigned koff = ((unsigned)(kk * 64 + hi * 16)) ^ ((unsigned)(lr & 7) << 4);
      bf16x8 af[4], bfr[4];
#pragma unroll
      for (int mi = 0; mi < 4; ++mi)
        af[mi] = *(const bf16x8*)((const char*)Asm + (size_t)(wm * 64 + mi * 16 + lr) * 128 + koff);
#pragma unroll
      for (int ni = 0; ni < 4; ++ni)
        bfr[ni] = *(const bf16x8*)((const char*)Bsm + (size_t)(wn * 64 + ni * 16 + lr) * 128 + koff);
#pragma unroll
      for (int mi = 0; mi < 4; ++mi)
#pragma unroll
        for (int ni = 0; ni < 4; ++ni)
          acc[mi][ni] = MFMA16(af[mi], bfr[ni], acc[mi][ni]);
    }
    __syncthreads();
  }

  // epilogue: + bias, cast bf16, scatter to [b][h][s][d]
#pragma unroll
  for (int ni = 0; ni < 4; ++ni) {
    int col = n0 + wn * 64 + ni * 16 + lr;
    float bia = bias[col];
    int h = col >> 6, d = col & 63;
#pragma unroll
    for (int mi = 0; mi < 4; ++mi) {
#pragma unroll
      for (int r = 0; r < 4; ++r) {
        int row = m0 + wm * 64 + mi * 16 + hi * 4 + r;  // = b*S + s
        int b = row >> 10, s = row & 1023;
        float val = acc[mi][ni][r] + bia;
        Out[((size_t)(b * NHEAD + h) * SS + s) * HDIM + d] = (bf16_t)val;
      }
    }
  }
}

// ---------------- V [bh][s][d] -> Vt [bh][d][s] ----------------
__global__ __launch_bounds__(256) void vtrans_kernel(const bf16_t* __restrict__ V,
                                                     bf16_t* __restrict__ Vt) {
  __shared__ bf16_t T[64 * 72];
  const int bh = blockIdx.y;
  const int s0 = blockIdx.x * 64;
  const int t = threadIdx.x;
  const bf16_t* Vb = V + (size_t)bh * SS * HDIM;
  bf16_t* Vtb = Vt + (size_t)bh * HDIM * SS;
#pragma unroll
  for (int it = 0; it < 2; ++it) {
    int idx = t + it * 256;
    int sl = idx >> 3;
    int dc = (idx & 7) * 8;
    *(int4*)&T[sl * 72 + dc] = *(const int4*)&Vb[(size_t)(s0 + sl) * HDIM + dc];
  }
  __syncthreads();
#pragma unroll
  for (int it = 0; it < 2; ++it) {
    int idx = t + it * 256;
    int d = idx >> 3;
    int sc = (idx & 7) * 8;
    union { int4 i4; bf16_t h[8]; } u;
#pragma unroll
    for (int e = 0; e < 8; ++e) u.h[e] = T[(sc + e) * 72 + d];
    *(int4*)&Vtb[(size_t)d * SS + s0 + sc] = u.i4;
  }
}

// ---------------- fused flash attention (swapped QK^T, 32x32 MFMA) ----------------
__global__ __launch_bounds__(256) void attn2_kernel(const bf16_t* __restrict__ Q,
                                                    const bf16_t* __restrict__ K,
                                                    const bf16_t* __restrict__ Vt,
                                                    const float* __restrict__ mask,
                                                    float* __restrict__ out) {
  __shared__ bf16_t Ksm[64 * 64];
  __shared__ bf16_t Vsm[64 * 64];
  __shared__ float Msm[SS];

  // chunked XCD swizzle: 512 wgs, 64 per XCD; x fastest -> one bh's K/V on one XCD
  const int wg = blockIdx.x;
  const int swzid = (wg & 7) * 64 + (wg >> 3);
  const int xblk = swzid & 7;
  const int bh = swzid >> 3;

  const int b = bh >> 4;
  const int h = bh & 15;
  const int t = threadIdx.x;
  const int lane = t & 63;
  const int w = t >> 6;
  const int l31 = lane & 31;
  const int hi = lane >> 5;
  const int q0 = xblk * 128 + w * 32;

  const bf16_t* Qh = Q + (size_t)bh * SS * HDIM;
  const bf16_t* Kh = K + (size_t)bh * SS * HDIM;
  const bf16_t* Vh = Vt + (size_t)bh * HDIM * SS;  // [d][s]

  *(float4*)&Msm[t * 4] = *(const float4*)&mask[(size_t)b * SS + t * 4];

  bf16x8 qb[4];
#pragma unroll
  for (int c = 0; c < 4; ++c)
    qb[c] = *(const bf16x8*)&Qh[(size_t)(q0 + l31) * HDIM + c * 16 + hi * 8];

  const int srow = lane >> 3;
  const unsigned gcol = ((lane & 7) * 16) ^ (srow << 4);
  const unsigned swz = (unsigned)((l31 & 7) << 4);

  f32x16 acc0 = {}, acc1 = {};
  float m_run = -1e30f, l_run = 0.f;

  for (int kv0 = 0; kv0 < SS; kv0 += 64) {
#pragma unroll
    for (int i = 0; i < 2; ++i) {
      int rbase = w * 16 + i * 8;
      gload_lds16((const char*)Kh + (size_t)(kv0 + rbase + srow) * 128 + gcol,
                  (char*)Ksm + (size_t)rbase * 128);
      gload_lds16((const char*)Vh + (size_t)(rbase + srow) * 2048 + (size_t)kv0 * 2 + gcol,
                  (char*)Vsm + (size_t)rbase * 128);
    }
    __syncthreads();

#pragma unroll
    for (int j = 0; j < 2; ++j) {
      f32x16 st = {};
#pragma unroll
      for (int c = 0; c < 4; ++c) {
        bf16x8 kf = *(const bf16x8*)((const char*)Ksm + (size_t)(j * 32 + l31) * 128 +
                                     ((unsigned)(c * 32 + hi * 16) ^ swz));
        st = MFMA32(kf, qb[c], st);
      }
#pragma unroll
      for (int k2 = 0; k2 < 8; ++k2) {
        int off = 8 * (k2 >> 1) + 4 * hi + 2 * (k2 & 1);
        float2 mk = *(const float2*)&Msm[kv0 + j * 32 + off];
        st[2 * k2] = st[2 * k2] * 0.125f + mk.x;
        st[2 * k2 + 1] = st[2 * k2 + 1] * 0.125f + mk.y;
      }
      float mj = st[0];
#pragma unroll
      for (int r = 1; r < 16; ++r) mj = fmaxf(mj, st[r]);
      mj = fmaxf(mj, __shfl_xor(mj, 32));
      if (!__all(mj <= m_run + 8.f)) {
        float mnew = fmaxf(m_run, mj);
        float corr = __expf(m_run - mnew);
#pragma unroll
        for (int r = 0; r < 16; ++r) { acc0[r] *= corr; acc1[r] *= corr; }
        l_run *= corr;
        m_run = mnew;
      }
      float ls = 0.f;
#pragma unroll
      for (int r = 0; r < 16; ++r) {
        float p = __expf(st[r] - m_run);
        st[r] = p;
        ls += p;
      }
      ls += __shfl_xor(ls, 32);
      l_run += ls;
      unsigned wd[8];
#pragma unroll
      for (int k2 = 0; k2 < 8; ++k2) {
        float lo = st[2 * k2], hip = st[2 * k2 + 1];
        unsigned r;
        asm("v_cvt_pk_bf16_f32 %0, %1, %2" : "=v"(r) : "v"(lo), "v"(hip));
        wd[k2] = r;
      }
      unsigned a0 = wd[0], b0 = wd[2]; PSWAP(a0, b0);
      unsigned a1 = wd[1], b1 = wd[3]; PSWAP(a1, b1);
      unsigned a2 = wd[4], b2 = wd[6]; PSWAP(a2, b2);
      unsigned a3 = wd[5], b3 = wd[7]; PSWAP(a3, b3);
      union { unsigned u[4]; bf16x8 v; } pf0, pf1;
      pf0.u[0] = a0; pf0.u[1] = a1; pf0.u[2] = b0; pf0.u[3] = b1;
      pf1.u[0] = a2; pf1.u[1] = a3; pf1.u[2] = b2; pf1.u[3] = b3;
#pragma unroll
      for (int kvc = 0; kvc < 2; ++kvc) {
        bf16x8 pf = (kvc == 0) ? pf0.v : pf1.v;
#pragma unroll
        for (int dch = 0; dch < 2; ++dch) {
          bf16x8 vf = *(const bf16x8*)((const char*)Vsm + (size_t)(dch * 32 + l31) * 128 +
                                       ((unsigned)(j * 64 + kvc * 32 + hi * 16) ^ swz));
          if (dch == 0) acc0 = MFMA32(vf, pf, acc0);
          else          acc1 = MFMA32(vf, pf, acc1);
        }
      }
    }
    __syncthreads();
  }

  float rinv = 1.0f / l_run;
  int q = q0 + l31;
  float* ob = out + ((size_t)(b * SS + q)) * HH + h * HDIM;
#pragma unroll
  for (int g = 0; g < 4; ++g) {
    float4 o0, o1;
    o0.x = acc0[g * 4 + 0] * rinv; o0.y = acc0[g * 4 + 1] * rinv;
    o0.z = acc0[g * 4 + 2] * rinv; o0.w = acc0[g * 4 + 3] * rinv;
    o1.x = acc1[g * 4 + 0] * rinv; o1.y = acc1[g * 4 + 1] * rinv;
    o1.z = acc1[g * 4 + 2] * rinv; o1.w = acc1[g * 4 + 3] * rinv;
    *(float4*)&ob[g * 8 + 4 * hi] = o0;
    *(float4*)&ob[32 + g * 8 + 4 * hi] = o1;
  }
}

// ---------------- launch ----------------
extern "C" void kernel_launch(void* const* d_in, const int* in_sizes, int n_in,
                              void* d_out, int out_size, void* d_ws, size_t ws_size,
                              hipStream_t stream) {
  const float* hs   = (const float*)d_in[0];
  const float* mask = (const float*)d_in[1];
  const float* Wq   = (const float*)d_in[2];
  const float* bq   = (const float*)d_in[3];
  const float* Wk   = (const float*)d_in[4];
  const float* bk   = (const float*)d_in[5];
  const float* Wv   = (const float*)d_in[6];
  const float* bv   = (const float*)d_in[7];
  float* out = (float*)d_out;

  char* ws = (char*)d_ws;
  bf16_t* hiddenB = (bf16_t*)ws;                                  // 8 MB (dead after GEMM)
  bf16_t* WT      = (bf16_t*)(ws + (size_t)8 * 1024 * 1024);      // 6 MB
  bf16_t* QKV     = (bf16_t*)(ws + (size_t)14 * 1024 * 1024);     // 24 MB
  bf16_t* Vt      = (bf16_t*)ws;                                  // reuse hiddenB region (8 MB)

  cvt_bf16_kernel<<<MM * HH / (256 * 8), 256, 0, stream>>>(hs, hiddenB, MM * HH);
  transposeW_kernel<<<dim3(32, 32, 3), dim3(32, 8), 0, stream>>>(Wq, Wk, Wv, WT);
  qkv_gemm_kernel<<<dim3(8 * 32 * 3), 256, 0, stream>>>(hiddenB, WT, bq, bk, bv, QKV);
  vtrans_kernel<<<dim3(SS / 64, BB * NHEAD), 256, 0, stream>>>(QKV + (size_t)2 * MM * HH, Vt);
  attn2_kernel<<<dim3(8 * BB * NHEAD), 256, 0, stream>>>(
      QKV, QKV + (size_t)MM * HH, Vt, mask, out);
}

// Round 4
// 86.790 us; speedup vs baseline: 1.6920x; 1.1620x over previous
//
#include <hip/hip_runtime.h>
#include <hip/hip_bf16.h>

typedef __bf16 bf16_t;
typedef __bf16 bf16x8 __attribute__((ext_vector_type(8)));
typedef float f32x4 __attribute__((ext_vector_type(4)));
typedef float f32x16 __attribute__((ext_vector_type(16)));
typedef unsigned uint2v __attribute__((ext_vector_type(2)));

#define MFMA16(a, b, c) __builtin_amdgcn_mfma_f32_16x16x32_bf16((a), (b), (c), 0, 0, 0)
#define MFMA32(a, b, c) __builtin_amdgcn_mfma_f32_32x32x16_bf16((a), (b), (c), 0, 0, 0)

static constexpr int BB = 4, SS = 1024, HH = 1024, NHEAD = 16, HDIM = 64;
static constexpr int MM = BB * SS;  // 4096

__device__ __forceinline__ void gload_lds16(const void* g, void* l) {
  __builtin_amdgcn_global_load_lds((const __attribute__((address_space(1))) void*)g,
                                   (__attribute__((address_space(3))) void*)l, 16, 0, 0);
}

#if __has_builtin(__builtin_amdgcn_permlane32_swap)
#define PSWAP(a, b)                                                    \
  {                                                                    \
    uint2v _r = __builtin_amdgcn_permlane32_swap((a), (b), false, false); \
    (a) = _r.x;                                                        \
    (b) = _r.y;                                                        \
  }
#else
#define PSWAP(a, b) asm("v_permlane32_swap_b32 %0, %1" : "+v"(a), "+v"(b))
#endif

// ---------------- fp32 -> bf16 convert (hidden) ----------------
__global__ __launch_bounds__(256) void cvt_bf16_kernel(const float* __restrict__ in,
                                                       bf16_t* __restrict__ out, int n) {
  int i = (blockIdx.x * 256 + threadIdx.x) * 8;
  if (i >= n) return;
  float4 a = *(const float4*)(in + i);
  float4 b = *(const float4*)(in + i + 4);
  union { int4 i4; bf16_t h[8]; } u;
  u.h[0] = (bf16_t)a.x; u.h[1] = (bf16_t)a.y; u.h[2] = (bf16_t)a.z; u.h[3] = (bf16_t)a.w;
  u.h[4] = (bf16_t)b.x; u.h[5] = (bf16_t)b.y; u.h[6] = (bf16_t)b.z; u.h[7] = (bf16_t)b.w;
  *(int4*)(out + i) = u.i4;
}

// ---------------- W [k][n] fp32 -> WT [n][k] bf16 ----------------
__global__ __launch_bounds__(256) void transposeW_kernel(const float* __restrict__ Wq,
                                                         const float* __restrict__ Wk,
                                                         const float* __restrict__ Wv,
                                                         bf16_t* __restrict__ WT) {
  __shared__ float tile[32][33];
  int z = blockIdx.z;
  const float* W = (z == 0) ? Wq : (z == 1) ? Wk : Wv;
  bf16_t* Out = WT + (size_t)z * HH * HH;
  int tx = threadIdx.x, ty = threadIdx.y;
  int x0 = blockIdx.x * 32;  // n
  int y0 = blockIdx.y * 32;  // k
  for (int j = ty; j < 32; j += 8)
    tile[j][tx] = W[(size_t)(y0 + j) * HH + x0 + tx];
  __syncthreads();
  for (int j = ty; j < 32; j += 8)
    Out[(size_t)(x0 + j) * HH + y0 + tx] = (bf16_t)tile[tx][j];
}

// ---------------- QKV projection GEMM: 3-buffer counted-vmcnt pipeline ----------------
// BM=256, BN=128, BK=64, 8 waves (4M x 2N), wave tile 64x64.
// K-tile j read from buf[j%3]; tile j+2 staged into buf[(j+2)%3] during tile j
// (that buffer's reads finished at the end-of-tile-(j-1) barrier -> race-free).
// One barrier + one counted vmcnt per K-tile; loads never drained to 0 mid-loop.
#define BM 256
#define BN 128
#define BKT 64
#define NT 16                               // K / BKT
#define BUF_ELEMS ((BM + BN) * BKT)         // 24576 bf16 = 48 KB

__global__ __launch_bounds__(512) void qkv_gemm2(const bf16_t* __restrict__ hiddenB,
                                                 const bf16_t* __restrict__ WT,
                                                 const float* __restrict__ bq,
                                                 const float* __restrict__ bk,
                                                 const float* __restrict__ bv,
                                                 bf16_t* __restrict__ Qo,
                                                 bf16_t* __restrict__ Ko,
                                                 bf16_t* __restrict__ Vt) {
  __shared__ bf16_t smem[3 * BUF_ELEMS];  // 144 KB

  // XCD swizzle: 384 wgs = 8 XCD x 48 (bijective); id ordered (z, mblk, nblk)
  const int wg = blockIdx.x;
  const int id = (wg & 7) * 48 + (wg >> 3);
  const int z = id >> 7;
  const int rem = id & 127;
  const int mblk = rem >> 3;
  const int nblk = rem & 7;

  const int m0 = mblk * BM;
  const int n0 = nblk * BN;
  const bf16_t* Wz = WT + (size_t)z * HH * HH;
  const char* Ag = (const char*)hiddenB + (size_t)m0 * 2048;
  const char* Bg = (const char*)Wz + (size_t)n0 * 2048;

  const int t = threadIdx.x;
  const int lane = t & 63;
  const int w = t >> 6;   // 0..7
  const int wr = w >> 1;  // 0..3 (M)
  const int wc = w & 1;   // 0..1 (N)
  const int lr = lane & 15;
  const int g4 = lane >> 4;  // 0..3

  const int srow = lane >> 3;  // 0..7
  const unsigned schunk = (((unsigned)(lane & 7)) ^ (unsigned)srow) << 4;
  const unsigned axor = ((unsigned)(lr & 7)) << 4;

  // stage one 16KB unit (128 rows x 128B) of tile kt: 2 gloads per wave
  auto stage_unit = [&](const char* gb, int growbase, int kt, char* ldsbase) {
    const size_t kof = (size_t)kt * 128;
    gload_lds16(gb + (size_t)(growbase + w * 8 + srow) * 2048 + kof + schunk,
                ldsbase + (w * 8) * 128);
    gload_lds16(gb + (size_t)(growbase + 64 + w * 8 + srow) * 2048 + kof + schunk,
                ldsbase + (64 + w * 8) * 128);
  };
  auto rdA = [&](const char* Ab, int mi, int ks) -> bf16x8 {
    unsigned off = ((unsigned)(ks * 64 + g4 * 16)) ^ axor;
    return *(const bf16x8*)(Ab + (size_t)(wr * 64 + mi * 16 + lr) * 128 + off);
  };
  auto rdB = [&](const char* Bb, int ni, int ks) -> bf16x8 {
    unsigned off = ((unsigned)(ks * 64 + g4 * 16)) ^ axor;
    return *(const bf16x8*)(Bb + (size_t)(wc * 64 + ni * 16 + lr) * 128 + off);
  };

  f32x4 acc[4][4] = {};

  // prologue: stage tiles 0 and 1
  {
    char* S0 = (char*)smem;
    stage_unit(Ag, 0, 0, S0);
    stage_unit(Ag, 128, 0, S0 + 16384);
    stage_unit(Bg, 0, 0, S0 + 32768);
    char* S1 = (char*)(smem + BUF_ELEMS);
    stage_unit(Ag, 0, 1, S1);
    stage_unit(Ag, 128, 1, S1 + 16384);
    stage_unit(Bg, 0, 1, S1 + 32768);
  }
  asm volatile("s_waitcnt vmcnt(6)" ::: "memory");
  __builtin_amdgcn_s_barrier();

  bf16x8 a01[2][2], a23[2][2], b01[2][2], b23[2][2];

  for (int j = 0; j < NT; ++j) {
    const int jb = j % 3;
    const int sb = (j + 2) % 3;
    const char* Ab = (const char*)(smem + jb * BUF_ELEMS);
    const char* Bb = Ab + 32768;
    char* Sb = (char*)(smem + sb * BUF_ELEMS);
    const bool st = (j + 2 < NT);

    // phase 0: stage A-half0(j+2); quadrant (mi 0-1, ni 0-1)
    if (st) stage_unit(Ag, 0, j + 2, Sb);
#pragma unroll
    for (int mi = 0; mi < 2; ++mi)
#pragma unroll
      for (int ks = 0; ks < 2; ++ks) a01[mi][ks] = rdA(Ab, mi, ks);
#pragma unroll
    for (int ni = 0; ni < 2; ++ni)
#pragma unroll
      for (int ks = 0; ks < 2; ++ks) b01[ni][ks] = rdB(Bb, ni, ks);
    __builtin_amdgcn_s_setprio(1);
#pragma unroll
    for (int mi = 0; mi < 2; ++mi)
#pragma unroll
      for (int ni = 0; ni < 2; ++ni)
#pragma unroll
        for (int ks = 0; ks < 2; ++ks)
          acc[mi][ni] = MFMA16(a01[mi][ks], b01[ni][ks], acc[mi][ni]);
    __builtin_amdgcn_s_setprio(0);

    // phase 1: stage A-half1(j+2); quadrant (mi 0-1, ni 2-3)
    if (st) stage_unit(Ag, 128, j + 2, Sb + 16384);
#pragma unroll
    for (int ni = 0; ni < 2; ++ni)
#pragma unroll
      for (int ks = 0; ks < 2; ++ks) b23[ni][ks] = rdB(Bb, 2 + ni, ks);
    __builtin_amdgcn_s_setprio(1);
#pragma unroll
    for (int mi = 0; mi < 2; ++mi)
#pragma unroll
      for (int ni = 0; ni < 2; ++ni)
#pragma unroll
        for (int ks = 0; ks < 2; ++ks)
          acc[mi][2 + ni] = MFMA16(a01[mi][ks], b23[ni][ks], acc[mi][2 + ni]);
    __builtin_amdgcn_s_setprio(0);

    // phase 2: stage B(j+2); quadrant (mi 2-3, ni 0-1)
    if (st) stage_unit(Bg, 0, j + 2, Sb + 32768);
#pragma unroll
    for (int mi = 0; mi < 2; ++mi)
#pragma unroll
      for (int ks = 0; ks < 2; ++ks) a23[mi][ks] = rdA(Ab, 2 + mi, ks);
    __builtin_amdgcn_s_setprio(1);
#pragma unroll
    for (int mi = 0; mi < 2; ++mi)
#pragma unroll
      for (int ni = 0; ni < 2; ++ni)
#pragma unroll
        for (int ks = 0; ks < 2; ++ks)
          acc[2 + mi][ni] = MFMA16(a23[mi][ks], b01[ni][ks], acc[2 + mi][ni]);
    __builtin_amdgcn_s_setprio(0);

    // phase 3: quadrant (mi 2-3, ni 2-3)
    __builtin_amdgcn_s_setprio(1);
#pragma unroll
    for (int mi = 0; mi < 2; ++mi)
#pragma unroll
      for (int ni = 0; ni < 2; ++ni)
#pragma unroll
        for (int ks = 0; ks < 2; ++ks)
          acc[2 + mi][2 + ni] = MFMA16(a23[mi][ks], b23[ni][ks], acc[2 + mi][2 + ni]);
    __builtin_amdgcn_s_setprio(0);

    if (j < NT - 2) {
      asm volatile("s_waitcnt vmcnt(6)" ::: "memory");
      __builtin_amdgcn_s_barrier();
    } else if (j == NT - 2) {
      asm volatile("s_waitcnt vmcnt(0)" ::: "memory");
      __builtin_amdgcn_s_barrier();
    }
  }

  // epilogue
  const float* bias = (z == 0) ? bq : (z == 1) ? bk : bv;
  if (z < 2) {
    bf16_t* Out = (z == 0) ? Qo : Ko;
#pragma unroll
    for (int ni = 0; ni < 4; ++ni) {
      int col = n0 + wc * 64 + ni * 16 + lr;
      float bia = bias[col];
      int hh = col >> 6, d = col & 63;
#pragma unroll
      for (int mi = 0; mi < 4; ++mi) {
#pragma unroll
        for (int r = 0; r < 4; ++r) {
          int row = m0 + wr * 64 + mi * 16 + g4 * 4 + r;
          int b = row >> 10, s = row & 1023;
          Out[((size_t)(b * NHEAD + hh) * SS + s) * HDIM + d] = (bf16_t)(acc[mi][ni][r] + bia);
        }
      }
    }
  } else {
    // V written directly transposed: Vt[bh][d][s]
#pragma unroll
    for (int ni = 0; ni < 4; ++ni) {
      int col = n0 + wc * 64 + ni * 16 + lr;
      float bia = bias[col];
      int hh = col >> 6, d = col & 63;
#pragma unroll
      for (int mi = 0; mi < 4; ++mi) {
        int row0 = m0 + wr * 64 + mi * 16 + g4 * 4;
        int b = row0 >> 10, s0 = row0 & 1023;
        float v0 = acc[mi][ni][0] + bia, v1 = acc[mi][ni][1] + bia;
        float v2 = acc[mi][ni][2] + bia, v3 = acc[mi][ni][3] + bia;
        unsigned u0, u1;
        asm("v_cvt_pk_bf16_f32 %0, %1, %2" : "=v"(u0) : "v"(v0), "v"(v1));
        asm("v_cvt_pk_bf16_f32 %0, %1, %2" : "=v"(u1) : "v"(v2), "v"(v3));
        uint2 pv; pv.x = u0; pv.y = u1;
        *(uint2*)&Vt[((size_t)(b * NHEAD + hh) * HDIM + d) * SS + s0] = pv;
      }
    }
  }
}

// ---------------- fused flash attention (swapped QK^T, 32x32 MFMA) ----------------
__global__ __launch_bounds__(256) void attn2_kernel(const bf16_t* __restrict__ Q,
                                                    const bf16_t* __restrict__ K,
                                                    const bf16_t* __restrict__ Vt,
                                                    const float* __restrict__ mask,
                                                    float* __restrict__ out) {
  __shared__ bf16_t Ksm[64 * 64];
  __shared__ bf16_t Vsm[64 * 64];
  __shared__ float Msm[SS];

  // chunked XCD swizzle: 512 wgs, 64 per XCD; x fastest -> one bh's K/V on one XCD
  const int wg = blockIdx.x;
  const int swzid = (wg & 7) * 64 + (wg >> 3);
  const int xblk = swzid & 7;
  const int bh = swzid >> 3;

  const int b = bh >> 4;
  const int h = bh & 15;
  const int t = threadIdx.x;
  const int lane = t & 63;
  const int w = t >> 6;
  const int l31 = lane & 31;
  const int hi = lane >> 5;
  const int q0 = xblk * 128 + w * 32;

  const bf16_t* Qh = Q + (size_t)bh * SS * HDIM;
  const bf16_t* Kh = K + (size_t)bh * SS * HDIM;
  const bf16_t* Vh = Vt + (size_t)bh * HDIM * SS;  // [d][s]

  *(float4*)&Msm[t * 4] = *(const float4*)&mask[(size_t)b * SS + t * 4];

  bf16x8 qb[4];
#pragma unroll
  for (int c = 0; c < 4; ++c)
    qb[c] = *(const bf16x8*)&Qh[(size_t)(q0 + l31) * HDIM + c * 16 + hi * 8];

  const int srow = lane >> 3;
  const unsigned gcol = ((lane & 7) * 16) ^ (srow << 4);
  const unsigned swz = (unsigned)((l31 & 7) << 4);

  f32x16 acc0 = {}, acc1 = {};
  float m_run = -1e30f, l_run = 0.f;

  for (int kv0 = 0; kv0 < SS; kv0 += 64) {
#pragma unroll
    for (int i = 0; i < 2; ++i) {
      int rbase = w * 16 + i * 8;
      gload_lds16((const char*)Kh + (size_t)(kv0 + rbase + srow) * 128 + gcol,
                  (char*)Ksm + (size_t)rbase * 128);
      gload_lds16((const char*)Vh + (size_t)(rbase + srow) * 2048 + (size_t)kv0 * 2 + gcol,
                  (char*)Vsm + (size_t)rbase * 128);
    }
    __syncthreads();

#pragma unroll
    for (int j = 0; j < 2; ++j) {
      f32x16 st = {};
      __builtin_amdgcn_s_setprio(1);
#pragma unroll
      for (int c = 0; c < 4; ++c) {
        bf16x8 kf = *(const bf16x8*)((const char*)Ksm + (size_t)(j * 32 + l31) * 128 +
                                     ((unsigned)(c * 32 + hi * 16) ^ swz));
        st = MFMA32(kf, qb[c], st);
      }
      __builtin_amdgcn_s_setprio(0);
#pragma unroll
      for (int k2 = 0; k2 < 8; ++k2) {
        int off = 8 * (k2 >> 1) + 4 * hi + 2 * (k2 & 1);
        float2 mk = *(const float2*)&Msm[kv0 + j * 32 + off];
        st[2 * k2] = st[2 * k2] * 0.125f + mk.x;
        st[2 * k2 + 1] = st[2 * k2 + 1] * 0.125f + mk.y;
      }
      float mj = st[0];
#pragma unroll
      for (int r = 1; r < 16; ++r) mj = fmaxf(mj, st[r]);
      mj = fmaxf(mj, __shfl_xor(mj, 32));
      if (!__all(mj <= m_run + 8.f)) {
        float mnew = fmaxf(m_run, mj);
        float corr = __expf(m_run - mnew);
#pragma unroll
        for (int r = 0; r < 16; ++r) { acc0[r] *= corr; acc1[r] *= corr; }
        l_run *= corr;
        m_run = mnew;
      }
      float ls = 0.f;
#pragma unroll
      for (int r = 0; r < 16; ++r) {
        float p = __expf(st[r] - m_run);
        st[r] = p;
        ls += p;
      }
      ls += __shfl_xor(ls, 32);
      l_run += ls;
      unsigned wd[8];
#pragma unroll
      for (int k2 = 0; k2 < 8; ++k2) {
        float lo = st[2 * k2], hip = st[2 * k2 + 1];
        unsigned r;
        asm("v_cvt_pk_bf16_f32 %0, %1, %2" : "=v"(r) : "v"(lo), "v"(hip));
        wd[k2] = r;
      }
      unsigned a0 = wd[0], b0 = wd[2]; PSWAP(a0, b0);
      unsigned a1 = wd[1], b1 = wd[3]; PSWAP(a1, b1);
      unsigned a2 = wd[4], b2 = wd[6]; PSWAP(a2, b2);
      unsigned a3 = wd[5], b3 = wd[7]; PSWAP(a3, b3);
      union { unsigned u[4]; bf16x8 v; } pf0, pf1;
      pf0.u[0] = a0; pf0.u[1] = a1; pf0.u[2] = b0; pf0.u[3] = b1;
      pf1.u[0] = a2; pf1.u[1] = a3; pf1.u[2] = b2; pf1.u[3] = b3;
      __builtin_amdgcn_s_setprio(1);
#pragma unroll
      for (int kvc = 0; kvc < 2; ++kvc) {
        bf16x8 pf = (kvc == 0) ? pf0.v : pf1.v;
#pragma unroll
        for (int dch = 0; dch < 2; ++dch) {
          bf16x8 vf = *(const bf16x8*)((const char*)Vsm + (size_t)(dch * 32 + l31) * 128 +
                                       ((unsigned)(j * 64 + kvc * 32 + hi * 16) ^ swz));
          if (dch == 0) acc0 = MFMA32(vf, pf, acc0);
          else          acc1 = MFMA32(vf, pf, acc1);
        }
      }
      __builtin_amdgcn_s_setprio(0);
    }
    __syncthreads();
  }

  float rinv = 1.0f / l_run;
  int q = q0 + l31;
  float* ob = out + ((size_t)(b * SS + q)) * HH + h * HDIM;
#pragma unroll
  for (int g = 0; g < 4; ++g) {
    float4 o0, o1;
    o0.x = acc0[g * 4 + 0] * rinv; o0.y = acc0[g * 4 + 1] * rinv;
    o0.z = acc0[g * 4 + 2] * rinv; o0.w = acc0[g * 4 + 3] * rinv;
    o1.x = acc1[g * 4 + 0] * rinv; o1.y = acc1[g * 4 + 1] * rinv;
    o1.z = acc1[g * 4 + 2] * rinv; o1.w = acc1[g * 4 + 3] * rinv;
    *(float4*)&ob[g * 8 + 4 * hi] = o0;
    *(float4*)&ob[32 + g * 8 + 4 * hi] = o1;
  }
}

// ---------------- launch ----------------
extern "C" void kernel_launch(void* const* d_in, const int* in_sizes, int n_in,
                              void* d_out, int out_size, void* d_ws, size_t ws_size,
                              hipStream_t stream) {
  const float* hs   = (const float*)d_in[0];
  const float* mask = (const float*)d_in[1];
  const float* Wq   = (const float*)d_in[2];
  const float* bq   = (const float*)d_in[3];
  const float* Wk   = (const float*)d_in[4];
  const float* bk   = (const float*)d_in[5];
  const float* Wv   = (const float*)d_in[6];
  const float* bv   = (const float*)d_in[7];
  float* out = (float*)d_out;

  char* ws = (char*)d_ws;
  bf16_t* hiddenB = (bf16_t*)ws;                                  // 8 MB
  bf16_t* WT      = (bf16_t*)(ws + (size_t)8 * 1024 * 1024);      // 6 MB
  bf16_t* Qb      = (bf16_t*)(ws + (size_t)14 * 1024 * 1024);     // 8 MB
  bf16_t* Kb      = (bf16_t*)(ws + (size_t)22 * 1024 * 1024);     // 8 MB
  bf16_t* Vt      = (bf16_t*)(ws + (size_t)30 * 1024 * 1024);     // 8 MB

  cvt_bf16_kernel<<<MM * HH / (256 * 8), 256, 0, stream>>>(hs, hiddenB, MM * HH);
  transposeW_kernel<<<dim3(32, 32, 3), dim3(32, 8), 0, stream>>>(Wq, Wk, Wv, WT);
  qkv_gemm2<<<384, 512, 0, stream>>>(hiddenB, WT, bq, bk, bv, Qb, Kb, Vt);
  attn2_kernel<<<dim3(8 * BB * NHEAD), 256, 0, stream>>>(Qb, Kb, Vt, mask, out);
}